// Round 3
// baseline (1027.654 us; speedup 1.0000x reference)
//
#include <hip/hip_runtime.h>

// WaveNet on gfx950, fp16 MFMA path, round 3.
// Layer kernel: single K=256 pass, 2 barriers, async global_load_lds staging into
// XOR-swizzled LDS, rcp-based gate, fused direct epilogue, fixed absolute tiling.
// Head kernel: N=128, 4 mid-passes, persistent accumulators, direct stores.

#define TT 8192
#define HIDC 128
#define GOODC 2046
#define TGT 6146
#define NL 20

typedef _Float16 half8_t __attribute__((ext_vector_type(8)));
typedef _Float16 half4_t __attribute__((ext_vector_type(4)));
typedef float floatx4 __attribute__((ext_vector_type(4)));

__device__ __forceinline__ floatx4 mfma16(half8_t a, half8_t b, floatx4 c) {
  return __builtin_amdgcn_mfma_f32_16x16x32_f16(a, b, c, 0, 0, 0);
}

__device__ __forceinline__ void gload_lds16(const _Float16* g, _Float16* l) {
  __builtin_amdgcn_global_load_lds(
      (const __attribute__((address_space(1))) unsigned int*)(const void*)g,
      (__attribute__((address_space(3))) unsigned int*)(void*)l, 16, 0, 0);
}

__device__ __forceinline__ float fast_sigmoid(float x) {
  return __builtin_amdgcn_rcpf(1.0f + __expf(-x));
}
__device__ __forceinline__ float fast_tanh(float x) {
  return 2.0f * __builtin_amdgcn_rcpf(1.0f + __expf(-2.0f * x)) - 1.0f;
}

// ---------------- weight prep: fp32 -> fp16, stacked layouts ----------------
__global__ void prep_kernel(const float* __restrict__ Wi, const float* __restrict__ Wf,
                            const float* __restrict__ Wg, const float* __restrict__ Wr,
                            const float* __restrict__ W1, const float* __restrict__ W2,
                            _Float16* __restrict__ WIh, _Float16* __restrict__ WFG,
                            _Float16* __restrict__ WRh, _Float16* __restrict__ W1h,
                            _Float16* __restrict__ W2h) {
  int idx = blockIdx.x * blockDim.x + threadIdx.x;
  int stride = gridDim.x * blockDim.x;
  // WFG[l][m][k]: m<128 -> Wf row m, else Wg row m-128; k<128 -> tap0 (u-d), else tap1 (u)
  for (int i = idx; i < NL * 256 * 256; i += stride) {
    int l = i >> 16; int m = (i >> 8) & 255; int k = i & 255;
    int tap = k >> 7; int ci = k & 127;
    float v;
    if (m < 128) v = Wf[(((size_t)l * 128 + m) * 128 + ci) * 2 + tap];
    else         v = Wg[(((size_t)l * 128 + (m - 128)) * 128 + ci) * 2 + tap];
    WFG[i] = (_Float16)v;
  }
  for (int i = idx; i < NL * 128 * 128; i += stride) WRh[i] = (_Float16)Wr[i];
  for (int i = idx; i < 128 * 256; i += stride) WIh[i] = (_Float16)Wi[i];
  for (int i = idx; i < 512 * 128; i += stride) W1h[i] = (_Float16)W1[i];
  for (int i = idx; i < 256 * 512; i += stride) W2h[i] = (_Float16)W2[i];
}

// ---------------- input 1x1 conv: R0[b][u][c] = Wi @ inputs + bi (fp16 out) ----------------
__global__ __launch_bounds__(256, 3) void input_kernel(
    const float* __restrict__ inp, const _Float16* __restrict__ WIh,
    const float* __restrict__ bi, _Float16* __restrict__ R0) {
  __shared__ __align__(16) _Float16 Xs[64][264];
  const int tid = threadIdx.x;
  const int lane = tid & 63;
  const int w = tid >> 6;
  const int ml = lane & 15;
  const int mq = lane >> 4;
  const int b = blockIdx.y;
  const int u0 = blockIdx.x * 64;
  const float* ib = inp + (size_t)b * 256 * TT;

  for (int i = tid; i < 64 * 16; i += 256) {
    int n4 = i & 15;
    int kg = i >> 4;
    const float* src = ib + (size_t)(kg * 4) * TT + u0 + n4 * 4;
    floatx4 c0 = *(const floatx4*)(src);
    floatx4 c1 = *(const floatx4*)(src + TT);
    floatx4 c2 = *(const floatx4*)(src + 2 * TT);
    floatx4 c3 = *(const floatx4*)(src + 3 * TT);
#pragma unroll
    for (int t = 0; t < 4; ++t) {
      half4_t h;
      h[0] = (_Float16)c0[t]; h[1] = (_Float16)c1[t];
      h[2] = (_Float16)c2[t]; h[3] = (_Float16)c3[t];
      *(half4_t*)&Xs[n4 * 4 + t][kg * 4] = h;
    }
  }
  __syncthreads();

  floatx4 acc[2][4];
#pragma unroll
  for (int a = 0; a < 2; ++a)
#pragma unroll
    for (int c = 0; c < 4; ++c) acc[a][c] = floatx4{0.f, 0.f, 0.f, 0.f};

  const _Float16* Aw = WIh + (size_t)(32 * w + ml) * 256;
  for (int kk = 0; kk < 8; ++kk) {
    const int ko = kk * 32 + mq * 8;
    half8_t a0 = *(const half8_t*)(Aw + ko);
    half8_t a1 = *(const half8_t*)(Aw + 16 * 256 + ko);
#pragma unroll
    for (int nt = 0; nt < 4; ++nt) {
      half8_t bv = *(const half8_t*)&Xs[nt * 16 + ml][ko];
      acc[0][nt] = mfma16(a0, bv, acc[0][nt]);
      acc[1][nt] = mfma16(a1, bv, acc[1][nt]);
    }
  }
  __syncthreads();
  float* Xf = (float*)&Xs[0][0];
#pragma unroll
  for (int mt = 0; mt < 2; ++mt) {
    const int mb = 32 * w + mt * 16 + mq * 4;
#pragma unroll
    for (int nt = 0; nt < 4; ++nt)
      *(floatx4*)&Xf[(nt * 16 + ml) * 132 + mb] = acc[mt][nt];
  }
  __syncthreads();
  _Float16* Rb = R0 + (size_t)b * TT * HIDC;
  for (int i = tid; i < 64 * 16; i += 256) {
    int n = i >> 4; int c = i & 15;
    floatx4 x0 = *(const floatx4*)&Xf[n * 132 + c * 8];
    floatx4 x1 = *(const floatx4*)&Xf[n * 132 + c * 8 + 4];
    floatx4 b0 = *(const floatx4*)(bi + c * 8);
    floatx4 b1v = *(const floatx4*)(bi + c * 8 + 4);
    half8_t h;
#pragma unroll
    for (int t = 0; t < 4; ++t) {
      h[t] = (_Float16)(x0[t] + b0[t]);
      h[4 + t] = (_Float16)(x1[t] + b1v[t]);
    }
    *(half8_t*)(Rb + (size_t)(u0 + n) * HIDC + c * 8) = h;
  }
}

// ---------------- one residual layer: N=96 absolute tile, single K=256 pass ----------------
// Xs: XOR-swizzled [96 rows][32 groups of 8 halves], phys group = lg ^ (n&7).
// logical k<128 -> tap0 (u-d), k>=128 -> tap1 (u) (doubles as R_old for the residual).
__global__ __launch_bounds__(512, 4) void layer_kernel(
    const _Float16* __restrict__ Rin, _Float16* __restrict__ Rout,
    const _Float16* __restrict__ WFG, const _Float16* __restrict__ WR,
    const float* __restrict__ bf, const float* __restrict__ bg,
    const float* __restrict__ br, int d, int ustart) {
  __shared__ __align__(16) _Float16 Xs[96 * 256];   // 49152 B, swizzled, no pad
  __shared__ __align__(16) _Float16 Os[96][136];    // 26112 B, padded
  const int tid = threadIdx.x;
  const int lane = tid & 63;
  const int w = tid >> 6;   // 0..7
  const int wm = w & 3;     // m-group
  const int wn = w >> 2;    // n-half (48 each)
  const int ml = lane & 15;
  const int mq = lane >> 4;
  const int b = blockIdx.y;
  const int u0 = blockIdx.x * 96;               // absolute tiling, stable across layers
  if (u0 + 95 < ustart) return;                  // tile entirely below valid range
  const _Float16* Rb = Rin + (size_t)b * TT * HIDC;
  _Float16* Ro = Rout + (size_t)b * TT * HIDC;

  // ---- async staging: 3072 chunks of 16B, 6 per lane ----
#pragma unroll
  for (int it = 0; it < 6; ++it) {
    int chunk = (w * 6 + it) * 64 + lane;
    int n = chunk >> 5;
    int pg = chunk & 31;
    int lg = pg ^ (n & 7);
    int tap = lg >> 4;
    int c8 = (lg & 15) << 3;
    int u = u0 + n - (tap ? 0 : d);
    u = min(max(u, 0), TT - 1);
    gload_lds16(Rb + (size_t)u * HIDC + c8, &Xs[(w * 6 + it) * 512]);
  }
  __syncthreads();

  // ---- GEMM1: [f;g](256) x K=256, wave wm owns f-rows & g-rows [32wm,32wm+32) ----
  floatx4 accF[2][3], accG[2][3];
#pragma unroll
  for (int a = 0; a < 2; ++a)
#pragma unroll
    for (int c = 0; c < 3; ++c) {
      accF[a][c] = floatx4{0.f, 0.f, 0.f, 0.f};
      accG[a][c] = floatx4{0.f, 0.f, 0.f, 0.f};
    }
  const _Float16* Af = WFG + (size_t)(32 * wm + ml) * 256;
  const _Float16* Ag = Af + 128 * 256;
  for (int kk = 0; kk < 8; ++kk) {
    const int ko = kk * 32 + mq * 8;
    const int g = ko >> 3;
    half8_t aF0 = *(const half8_t*)(Af + ko);
    half8_t aF1 = *(const half8_t*)(Af + 16 * 256 + ko);
    half8_t aG0 = *(const half8_t*)(Ag + ko);
    half8_t aG1 = *(const half8_t*)(Ag + 16 * 256 + ko);
#pragma unroll
    for (int nt = 0; nt < 3; ++nt) {
      const int row = wn * 48 + nt * 16 + ml;
      half8_t bv = *(const half8_t*)&Xs[row * 256 + ((g ^ (row & 7)) << 3)];
      accF[0][nt] = mfma16(aF0, bv, accF[0][nt]);
      accF[1][nt] = mfma16(aF1, bv, accF[1][nt]);
      accG[0][nt] = mfma16(aG0, bv, accG[0][nt]);
      accG[1][nt] = mfma16(aG1, bv, accG[1][nt]);
    }
  }

  // ---- gate: out = tanh(f+bf)*sigmoid(g+bg) -> Os ----
#pragma unroll
  for (int mt = 0; mt < 2; ++mt) {
    const int mb = 32 * wm + mt * 16 + mq * 4;
    floatx4 bfv = *(const floatx4*)(bf + mb);
    floatx4 bgv = *(const floatx4*)(bg + mb);
#pragma unroll
    for (int nt = 0; nt < 3; ++nt) {
      half4_t o;
#pragma unroll
      for (int r = 0; r < 4; ++r) {
        float fv = fast_tanh(accF[mt][nt][r] + bfv[r]);
        float gv = fast_sigmoid(accG[mt][nt][r] + bgv[r]);
        o[r] = (_Float16)(fv * gv);
      }
      *(half4_t*)&Os[wn * 48 + nt * 16 + ml][mb] = o;
    }
  }
  __syncthreads();

  // ---- GEMM2: x = WR(128x128) @ out ----
  floatx4 accX[2][3];
#pragma unroll
  for (int a = 0; a < 2; ++a)
#pragma unroll
    for (int c = 0; c < 3; ++c) accX[a][c] = floatx4{0.f, 0.f, 0.f, 0.f};
  const _Float16* Ar = WR + (size_t)(32 * wm + ml) * 128;
#pragma unroll
  for (int kk = 0; kk < 4; ++kk) {
    const int ko = kk * 32 + mq * 8;
    half8_t a0 = *(const half8_t*)(Ar + ko);
    half8_t a1 = *(const half8_t*)(Ar + 16 * 128 + ko);
#pragma unroll
    for (int nt = 0; nt < 3; ++nt) {
      half8_t bv = *(const half8_t*)&Os[wn * 48 + nt * 16 + ml][ko];
      accX[0][nt] = mfma16(a0, bv, accX[0][nt]);
      accX[1][nt] = mfma16(a1, bv, accX[1][nt]);
    }
  }

  // ---- fused epilogue: R_new = x + br + R_old (tap1 half of Xs), direct store ----
#pragma unroll
  for (int mt = 0; mt < 2; ++mt) {
    const int mb = 32 * wm + mt * 16 + mq * 4;
    floatx4 brv = *(const floatx4*)(br + mb);
    const int lgT = 16 + (mb >> 3);
    const int off = mb & 7;
#pragma unroll
    for (int nt = 0; nt < 3; ++nt) {
      const int n = wn * 48 + nt * 16 + ml;
      const int u = u0 + n;
      if (u >= ustart && u < TT) {
        half4_t rold = *(const half4_t*)&Xs[n * 256 + ((lgT ^ (n & 7)) << 3) + off];
        half4_t o;
#pragma unroll
        for (int r = 0; r < 4; ++r)
          o[r] = (_Float16)(accX[mt][nt][r] + brv[r] + (float)rold[r]);
        *(half4_t*)(Ro + (size_t)u * HIDC + mb) = o;
      }
    }
  }
}

// ---------------- head: out = W2 @ relu(W1 @ relu(R20-R0) + b1) + b2 ----------------
// N=128/block, 4 mid-passes of 128, persistent GEMM2 accumulators, direct stores.
__global__ __launch_bounds__(512, 4) void head_kernel(
    const _Float16* __restrict__ Rfin, const _Float16* __restrict__ R0,
    const _Float16* __restrict__ W1h, const _Float16* __restrict__ W2h,
    const float* __restrict__ b1, const float* __restrict__ b2,
    float* __restrict__ out) {
  __shared__ __align__(16) _Float16 Hs[128][136];   // relu(final) [n][c=128]
  __shared__ __align__(16) _Float16 H1s[128][136];  // mid chunk [n][kc=128]
  const int tid = threadIdx.x;
  const int lane = tid & 63;
  const int w = tid >> 6;   // 0..7
  const int mg = w & 3;     // m-group
  const int ng = w >> 2;    // n-half (64 each)
  const int ml = lane & 15;
  const int mq = lane >> 4;
  const int b = blockIdx.y;
  const int u0 = GOODC + blockIdx.x * 128;
  const _Float16* Ra = Rfin + (size_t)b * TT * HIDC;
  const _Float16* Rz = R0 + (size_t)b * TT * HIDC;

  for (int i = tid; i < 128 * 16; i += 512) {
    int n = i >> 4; int c = i & 15;
    int u = u0 + n; if (u > TT - 1) u = TT - 1;
    half8_t a = *(const half8_t*)(Ra + (size_t)u * HIDC + c * 8);
    half8_t z = *(const half8_t*)(Rz + (size_t)u * HIDC + c * 8);
    half8_t h;
#pragma unroll
    for (int t = 0; t < 8; ++t) {
      float v = (float)a[t] - (float)z[t];
      h[t] = (_Float16)(v > 0.f ? v : 0.f);
    }
    *(half8_t*)&Hs[n][c * 8] = h;
  }
  __syncthreads();

  floatx4 accO[4][4];   // persistent: out rows mg*64+mt*16, n ng*64+nt*16
#pragma unroll
  for (int a = 0; a < 4; ++a)
#pragma unroll
    for (int c = 0; c < 4; ++c) accO[a][c] = floatx4{0.f, 0.f, 0.f, 0.f};

  for (int p = 0; p < 4; ++p) {
    // GEMM1: mid rows [128p,128p+128), wave owns 32 rows (mg*32) x n-half (64)
    floatx4 acc1[2][4];
#pragma unroll
    for (int a = 0; a < 2; ++a)
#pragma unroll
      for (int c = 0; c < 4; ++c) acc1[a][c] = floatx4{0.f, 0.f, 0.f, 0.f};
    const _Float16* A1 = W1h + (size_t)(128 * p + 32 * mg + ml) * 128;
#pragma unroll
    for (int kk = 0; kk < 4; ++kk) {
      const int ko = kk * 32 + mq * 8;
      half8_t av0 = *(const half8_t*)(A1 + ko);
      half8_t av1 = *(const half8_t*)(A1 + 16 * 128 + ko);
#pragma unroll
      for (int nt = 0; nt < 4; ++nt) {
        half8_t bv = *(const half8_t*)&Hs[ng * 64 + nt * 16 + ml][ko];
        acc1[0][nt] = mfma16(av0, bv, acc1[0][nt]);
        acc1[1][nt] = mfma16(av1, bv, acc1[1][nt]);
      }
    }
    __syncthreads();  // previous pass's H1s reads complete
#pragma unroll
    for (int mt = 0; mt < 2; ++mt) {
      const int kc = 32 * mg + mt * 16 + mq * 4;
      floatx4 bv = *(const floatx4*)(b1 + 128 * p + kc);
#pragma unroll
      for (int nt = 0; nt < 4; ++nt) {
        half4_t h;
#pragma unroll
        for (int r = 0; r < 4; ++r) {
          float v = acc1[mt][nt][r] + bv[r];
          h[r] = (_Float16)(v > 0.f ? v : 0.f);
        }
        *(half4_t*)&H1s[ng * 64 + nt * 16 + ml][kc] = h;
      }
    }
    __syncthreads();
    // GEMM2 accumulate: out rows mg*64..+64, K = this 128-chunk
    const _Float16* A2 = W2h + (size_t)(64 * mg + ml) * 512 + p * 128;
#pragma unroll
    for (int kk = 0; kk < 4; ++kk) {
      const int ko = kk * 32 + mq * 8;
#pragma unroll
      for (int nt = 0; nt < 4; ++nt) {
        half8_t bv = *(const half8_t*)&H1s[ng * 64 + nt * 16 + ml][ko];
#pragma unroll
        for (int mt = 0; mt < 4; ++mt) {
          half8_t av = *(const half8_t*)(A2 + (size_t)(mt * 16) * 512 + ko);
          accO[mt][nt] = mfma16(av, bv, accO[mt][nt]);
        }
      }
    }
  }

  // direct store: lane holds col=n (ml), rows m = mg*64+mt*16+mq*4+r
#pragma unroll
  for (int mt = 0; mt < 4; ++mt) {
    const int m = 64 * mg + mt * 16 + mq * 4;
    floatx4 b2v = *(const floatx4*)(b2 + m);
#pragma unroll
    for (int nt = 0; nt < 4; ++nt) {
      const int n = ng * 64 + nt * 16 + ml;
      const int u = u0 + n;
      if (u < TT) {
        *(floatx4*)(out + ((size_t)b * TGT + (u - GOODC)) * 256 + m) = accO[mt][nt] + b2v;
      }
    }
  }
}

extern "C" void kernel_launch(void* const* d_in, const int* in_sizes, int n_in,
                              void* d_out, int out_size, void* d_ws, size_t ws_size,
                              hipStream_t stream) {
  const float* inputs = (const float*)d_in[0];
  const float* Wi = (const float*)d_in[1];
  const float* bi = (const float*)d_in[2];
  const float* Wf = (const float*)d_in[3];
  const float* bf = (const float*)d_in[4];
  const float* Wg = (const float*)d_in[5];
  const float* bg = (const float*)d_in[6];
  const float* Wr = (const float*)d_in[7];
  const float* br = (const float*)d_in[8];
  const float* W1 = (const float*)d_in[9];
  const float* b1 = (const float*)d_in[10];
  const float* W2 = (const float*)d_in[11];
  const float* b2 = (const float*)d_in[12];
  float* out = (float*)d_out;

  // workspace layout (~54 MB): three fp16 res buffers + fp16 weights
  char* ws = (char*)d_ws;
  _Float16* R0h = (_Float16*)(ws + 0);
  _Float16* Ph  = (_Float16*)(ws + 16777216);
  _Float16* Qh  = (_Float16*)(ws + 33554432);
  _Float16* WFG = (_Float16*)(ws + 50331648);
  _Float16* WRh = (_Float16*)(ws + 52953088);
  _Float16* WIh = (_Float16*)(ws + 53608448);
  _Float16* W1h = (_Float16*)(ws + 53673984);
  _Float16* W2h = (_Float16*)(ws + 53805056);

  prep_kernel<<<dim3(512), dim3(256), 0, stream>>>(Wi, Wf, Wg, Wr, W1, W2,
                                                   WIh, WFG, WRh, W1h, W2h);
  input_kernel<<<dim3(TT / 64, 8), dim3(256), 0, stream>>>(inputs, WIh, bi, R0h);

  int S = 0;
  for (int l = 0; l < NL; ++l) {
    int d = 1 << (l % 10);
    int ustart = S + d;
    const _Float16* rin = (l == 0) ? R0h : ((l & 1) ? Ph : Qh);
    _Float16* rout = (l & 1) ? Qh : Ph;
    // fixed absolute tiling (86 tiles of 96) -> stable tile->XCD mapping
    layer_kernel<<<dim3(86, 8), dim3(512), 0, stream>>>(
        rin, rout, WFG + (size_t)l * 65536, WRh + (size_t)l * 16384,
        bf + l * 128, bg + l * 128, br + l * 128, d, ustart);
    S = ustart;
  }
  // after l=19 (odd), final res is in Qh
  head_kernel<<<dim3((TGT + 127) / 128, 8), dim3(512), 0, stream>>>(
      Qh, R0h, W1h, W2h, b1, b2, out);
}